// Round 6
// baseline (83.193 us; speedup 1.0000x reference)
//
#include <hip/hip_runtime.h>
#include <hip/hip_bf16.h>

typedef __attribute__((ext_vector_type(8))) short bf16x8;
typedef __attribute__((ext_vector_type(4))) float f32x4;

#define D_K    256
#define WH     784
#define P_REAL 511
#define P_PAD  512
#define C_OUT  200
#define NLEAF  512
#define TDEPTH 9

#define NTILES     13       // per (b, wh-half): 13 tiles x 32 cols (overlap/dup harmless for min)
#define TILE_USH   8192     // 32 n x 256 k ushorts = 16KB
#define TILE_BYTES 16384

// fixed workspace region (bytes)
#define WS_PB   0                          // 512*256*2       = 262144
#define WS_P2   262144                     // 512*4           = 2048
#define WS_DS   264192                     // 512*200*4       = 409600
#define WS_PM   673792                     // 128*2*512*4     = 524288
#define WS_FIX  1198080
// per-b chunk bytes: x2 2*13*32*4 = 3328 ; xsw 2*13*16384 = 425984
#define PER_B_X2   3328
#define PER_B_XSW  425984

static __device__ __forceinline__ unsigned short f2bf(float x) {
    union { float f; unsigned int u; } v; v.f = x;
    unsigned int r = v.u + 0x7FFFu + ((v.u >> 16) & 1u);   // RNE
    return (unsigned short)(r >> 16);
}

// async global->LDS, 16B per lane (lds dest = wave-uniform base + lane*16)
#define GLL16(G, L) __builtin_amdgcn_global_load_lds(                         \
        (const __attribute__((address_space(1))) void*)(G),                   \
        (__attribute__((address_space(3))) void*)(L), 16, 0, 0)

// --- fused prep (proto -> bf16(-2p) + p2) and softmax(leaf_params) --------
__global__ __launch_bounds__(64)
void prep2_kernel(const float* __restrict__ protos, const float* __restrict__ lp,
                  unsigned short* __restrict__ pb, float* __restrict__ p2,
                  float* __restrict__ ds) {
    int bid = blockIdx.x;
    int l = threadIdx.x;
    if (bid < P_PAD) {
        int p = bid;
        f32x4 v = {0.f, 0.f, 0.f, 0.f};
        if (p < P_REAL)
            v = *reinterpret_cast<const f32x4*>(protos + (size_t)p * D_K + 4 * l);
        ushort4 w;
        w.x = f2bf(-2.f * v[0]); w.y = f2bf(-2.f * v[1]);
        w.z = f2bf(-2.f * v[2]); w.w = f2bf(-2.f * v[3]);
        *reinterpret_cast<ushort4*>(pb + (size_t)p * D_K + 4 * l) = w;
        float s = v[0]*v[0] + v[1]*v[1] + v[2]*v[2] + v[3]*v[3];
#pragma unroll
        for (int m = 32; m >= 1; m >>= 1) s += __shfl_xor(s, m, 64);
        if (l == 0) p2[p] = s;
    } else {
        int row = bid - P_PAD;
        float v[4];
        float mx = -3.4e38f;
#pragma unroll
        for (int i = 0; i < 4; ++i) {
            int c = l + 64 * i;
            v[i] = (c < C_OUT) ? lp[(size_t)row * C_OUT + c] : -3.4e38f;
            mx = fmaxf(mx, v[i]);
        }
#pragma unroll
        for (int m = 32; m >= 1; m >>= 1) mx = fmaxf(mx, __shfl_xor(mx, m, 64));
        float sum = 0.f;
#pragma unroll
        for (int i = 0; i < 4; ++i) {
            int c = l + 64 * i;
            if (c < C_OUT) { v[i] = expf(v[i] - mx); sum += v[i]; }
        }
#pragma unroll
        for (int m = 32; m >= 1; m >>= 1) sum += __shfl_xor(sum, m, 64);
        float inv = 1.f / sum;
#pragma unroll
        for (int i = 0; i < 4; ++i) {
            int c = l + 64 * i;
            if (c < C_OUT) ds[(size_t)row * C_OUT + c] = v[i] * inv;
        }
    }
}

// --- pass 1: xs fp32 -> bf16, transposed + swizzled MFMA-ready tiles + x2 --
// element (n,k) of tile stored at ushort offset n*256 + (k ^ ((n&7)<<3))
// grid: NB*2*13 blocks (grp = bb*2+whh, tile t); 256 threads
__global__ __launch_bounds__(256)
void convert_kernel(const float* __restrict__ xs, int b0,
                    unsigned short* __restrict__ xsw,
                    float* __restrict__ x2arr) {
    __shared__ unsigned short T[32 * 256];   // 16 KB, already in output layout
    __shared__ float x2l[32][8];

    const int id  = blockIdx.x;
    const int t   = id % NTILES;
    const int grp = id / NTILES;             // local: bb*2 + whh
    const int whh = grp & 1;
    const int b   = b0 + (grp >> 1);

    const int tid = threadIdx.x;
    const int whl = tid & 31;                // column within tile
    const int dst = tid >> 5;                // d-strip (8 strips x 32)

    int wh = whh * 392 + t * 32 + whl;
    if (wh > WH - 1) wh = WH - 1;            // tail: duplicate last column

    const float* xb = xs + (size_t)b * (D_K * WH) + wh;
    const int xorm = (whl & 7) << 3;

    float x2p = 0.f;
#pragma unroll 8
    for (int i = 0; i < 32; ++i) {
        int d = dst * 32 + i;
        float v = xb[(size_t)d * WH];
        x2p += v * v;
        T[whl * 256 + (d ^ xorm)] = f2bf(v);
    }
    x2l[whl][dst] = x2p;
    __syncthreads();

    if (tid < 32) {
        float s = 0.f;
#pragma unroll
        for (int j = 0; j < 8; ++j) s += x2l[tid][j];
        x2arr[((size_t)grp * NTILES + t) * 32 + tid] = s;
    }

    // linear tile write-out (swizzle already applied in LDS layout)
    const uint4* Ts = reinterpret_cast<const uint4*>(T);
    uint4* dst4 = reinterpret_cast<uint4*>(xsw + ((size_t)grp * NTILES + t) * TILE_USH);
#pragma unroll
    for (int i = 0; i < 4; ++i)
        dst4[tid + 256 * i] = Ts[tid + 256 * i];
}

// --- pass 2: pm[b][whh][p] = min over tiles/cols of (x2[col] - 2*x.p) -----
// grid NB*4: id = xcd + 8*rest; ph = rest&1 (p-half), grpIdx = ((rest>>1)<<3)|xcd
// 4 waves x 64 p-rows; B staged via global_load_lds; double-buffer, 1 barrier/tile
__global__ __launch_bounds__(256, 2)
void gemm_min_kernel(const unsigned short* __restrict__ xsw,
                     const float* __restrict__ x2arr,
                     const unsigned short* __restrict__ pb,
                     float* __restrict__ pm, int b0) {
    __shared__ unsigned short Xs[2][TILE_USH];   // 32 KB

    const int tid  = threadIdx.x;
    const int wv   = tid >> 6;
    const int lane = tid & 63;
    const int g    = lane >> 4;
    const int lr   = lane & 15;

    const int id   = blockIdx.x;
    const int xcd  = id & 7;
    const int rest = id >> 3;
    const int ph   = rest & 1;
    const int grpI = ((rest >> 1) << 3) | xcd;   // local bb*2 + whh
    const int bb   = grpI >> 1;
    const int whh  = grpI & 1;
    const int p0   = ph * 256;

    const char*  tiles = (const char*)(xsw + (size_t)grpI * NTILES * TILE_USH);
    const float* x2t   = x2arr + (size_t)grpI * NTILES * 32;

    // A: -2*proto bf16, 64 rows x full K per wave, resident in regs/AGPRs
    bf16x8 af[4][8];
#pragma unroll
    for (int mf = 0; mf < 4; ++mf) {
        const unsigned short* rp = pb + (size_t)(p0 + 64*wv + 16*mf + lr) * D_K + 8*g;
#pragma unroll
        for (int ks = 0; ks < 8; ++ks)
            af[mf][ks] = *reinterpret_cast<const bf16x8*>(rp + 32*ks);
    }

    float rmin[4][4];
#pragma unroll
    for (int mf = 0; mf < 4; ++mf)
#pragma unroll
        for (int r = 0; r < 4; ++r) rmin[mf][r] = 3.0e38f;

#define STAGE(BUF, T) do {                                                    \
        const char* s_ = tiles + (size_t)(T) * TILE_BYTES + wv*4096 + lane*16;\
        unsigned short* l_ = &Xs[BUF][wv * 2048];                             \
        GLL16(s_,        l_);                                                 \
        GLL16(s_ + 1024, l_ + 512);                                           \
        GLL16(s_ + 2048, l_ + 1024);                                          \
        GLL16(s_ + 3072, l_ + 1536);                                          \
    } while (0)

    // prologue
    STAGE(0, 0);
    float x2n0 = x2t[lr], x2n1 = x2t[16 + lr];
    __syncthreads();

    int buf = 0;
    for (int t = 0; t < NTILES; ++t) {
        const bool more = (t + 1 < NTILES);
        if (more) STAGE(buf ^ 1, t + 1);

        const float x2v0 = x2n0, x2v1 = x2n1;
        if (more) {
            x2n0 = x2t[(t + 1) * 32 + lr];
            x2n1 = x2t[(t + 1) * 32 + 16 + lr];
        }

        f32x4 acc[4][2];
#pragma unroll
        for (int mf = 0; mf < 4; ++mf) {
            acc[mf][0] = (f32x4){x2v0, x2v0, x2v0, x2v0};
            acc[mf][1] = (f32x4){x2v1, x2v1, x2v1, x2v1};
        }

        __builtin_amdgcn_s_setprio(1);
#pragma unroll
        for (int ks = 0; ks < 8; ++ks) {
            bf16x8 bfr[2];
#pragma unroll
            for (int nf = 0; nf < 2; ++nf) {
                int n = 16*nf + lr;
                int off = n * 256 + (((ks << 2) + g) ^ (lr & 7)) * 8;
                bfr[nf] = *reinterpret_cast<const bf16x8*>(&Xs[buf][off]);
            }
#pragma unroll
            for (int mf = 0; mf < 4; ++mf)
#pragma unroll
                for (int nf = 0; nf < 2; ++nf)
                    acc[mf][nf] = __builtin_amdgcn_mfma_f32_16x16x32_bf16(
                        af[mf][ks], bfr[nf], acc[mf][nf], 0, 0, 0);
        }
        __builtin_amdgcn_s_setprio(0);

#pragma unroll
        for (int mf = 0; mf < 4; ++mf)
#pragma unroll
            for (int r = 0; r < 4; ++r)
                rmin[mf][r] = fminf(rmin[mf][r],
                                    fminf(acc[mf][0][r], acc[mf][1][r]));

        __syncthreads();
        buf ^= 1;
    }

    // min across the 16 column-lanes (flips only lr bits; g preserved)
#pragma unroll
    for (int mf = 0; mf < 4; ++mf)
#pragma unroll
        for (int r = 0; r < 4; ++r) {
            float v = rmin[mf][r];
#pragma unroll
            for (int m = 1; m <= 8; m <<= 1)
                v = fminf(v, __shfl_xor(v, m, 64));
            rmin[mf][r] = v;
        }

    if (lr == 0) {
        float* pmw = pm + (((size_t)(b0 + bb) * 2 + whh)) * P_PAD;
#pragma unroll
        for (int mf = 0; mf < 4; ++mf)
#pragma unroll
            for (int r = 0; r < 4; ++r)
                pmw[p0 + 64*wv + 16*mf + 4*g + r] = rmin[mf][r];
    }
#undef STAGE
}

// --- combine halves + exp(-sqrt) + tree path products + pa @ ds -----------
__global__ __launch_bounds__(256)
void out_kernel(const float* __restrict__ pm, const float* __restrict__ p2,
                const float* __restrict__ ds, float* __restrict__ out) {
    __shared__ float sim[NLEAF];
    __shared__ float pa[NLEAF];
    int b = blockIdx.x;
    int t = threadIdx.x;
    const float* pm0 = pm + (size_t)b * 2 * P_PAD;
#pragma unroll
    for (int j = 0; j < 2; ++j) {
        int p = t + 256 * j;
        float m = fminf(pm0[p], pm0[P_PAD + p]);
        float sq = m + p2[p];
        sim[p] = expf(-sqrtf(fabsf(sq) + 1e-14f));
    }
    __syncthreads();
#pragma unroll
    for (int j = 0; j < 2; ++j) {
        int leaf = t + 256 * j;
        int node = 0;
        float prod = 1.f;
#pragma unroll
        for (int st = 0; st < TDEPTH; ++st) {
            int bit = (leaf >> (TDEPTH - 1 - st)) & 1;
            float sv = sim[node];
            prod *= bit ? sv : (1.f - sv);
            node = 2 * node + 1 + bit;
        }
        pa[leaf] = prod;
    }
    __syncthreads();
    if (t < C_OUT) {
        float a0 = 0.f, a1 = 0.f, a2 = 0.f, a3 = 0.f;
        for (int l = 0; l < NLEAF; l += 4) {
            a0 += pa[l + 0] * ds[(size_t)(l + 0) * C_OUT + t];
            a1 += pa[l + 1] * ds[(size_t)(l + 1) * C_OUT + t];
            a2 += pa[l + 2] * ds[(size_t)(l + 2) * C_OUT + t];
            a3 += pa[l + 3] * ds[(size_t)(l + 3) * C_OUT + t];
        }
        out[(size_t)b * C_OUT + t] = (a0 + a1) + (a2 + a3);
    }
}

extern "C" void kernel_launch(void* const* d_in, const int* in_sizes, int n_in,
                              void* d_out, int out_size, void* d_ws, size_t ws_size,
                              hipStream_t stream) {
    (void)in_sizes; (void)n_in; (void)out_size;
    const float* xs     = (const float*)d_in[0];
    const float* protos = (const float*)d_in[1];
    const float* lp     = (const float*)d_in[2];
    float* out = (float*)d_out;

    char* ws = (char*)d_ws;
    unsigned short* pb = (unsigned short*)(ws + WS_PB);
    float* p2   = (float*)(ws + WS_P2);
    float* dsm  = (float*)(ws + WS_DS);
    float* pm   = (float*)(ws + WS_PM);

    // largest batch-chunk that fits the workspace (deterministic in ws_size)
    int NB = 4;
    const int cand[5] = {128, 64, 32, 16, 8};
    for (int i = 0; i < 5; ++i) {
        size_t need = (size_t)WS_FIX + (size_t)cand[i] * (PER_B_X2 + PER_B_XSW);
        if (need <= ws_size) { NB = cand[i]; break; }
    }
    float* x2arr = (float*)(ws + WS_FIX);
    unsigned short* xsw = (unsigned short*)(ws + WS_FIX + (size_t)NB * PER_B_X2);

    prep2_kernel<<<1024, 64, 0, stream>>>(protos, lp, pb, p2, dsm);
    for (int b0 = 0; b0 < 128; b0 += NB) {
        convert_kernel<<<NB * 2 * NTILES, 256, 0, stream>>>(xs, b0, xsw, x2arr);
        gemm_min_kernel<<<NB * 4, 256, 0, stream>>>(xsw, x2arr, pb, pm, b0);
    }
    out_kernel<<<128, 256, 0, stream>>>(pm, p2, dsm, out);
}

// Round 7
// 57.028 us; speedup vs baseline: 1.4588x; 1.4588x over previous
//
#include <hip/hip_runtime.h>
#include <hip/hip_bf16.h>

typedef __attribute__((ext_vector_type(8))) short bf16x8;
typedef __attribute__((ext_vector_type(4))) float f32x4;

#define D_K    256
#define WH     784
#define WHH    392
#define P_REAL 511
#define P_PAD  512
#define C_OUT  200
#define NLEAF  512
#define TDEPTH 9

#define NT      32
#define NTILES  13          // 13*32 >= 392 (tail clamped to duplicate columns)
#define TILE_USH 8192       // 32 n x 256 k ushorts = 16 KB

// workspace offsets (bytes)
#define WS_PB   0                          // 512*256*2   = 262144
#define WS_P2   262144                     // 512*4
#define WS_DS   264192                     // 512*200*4
#define WS_PM   673792                     // 128*2*512*4
// total 1198080

static __device__ __forceinline__ unsigned short f2bf(float x) {
    union { float f; unsigned int u; } v; v.f = x;
    unsigned int r = v.u + 0x7FFFu + ((v.u >> 16) & 1u);   // RNE
    return (unsigned short)(r >> 16);
}

// --- fused prep (proto -> bf16(-2p) + p2) and softmax(leaf_params) --------
__global__ __launch_bounds__(64)
void prep2_kernel(const float* __restrict__ protos, const float* __restrict__ lp,
                  unsigned short* __restrict__ pb, float* __restrict__ p2,
                  float* __restrict__ ds) {
    int bid = blockIdx.x;
    int l = threadIdx.x;
    if (bid < P_PAD) {
        int p = bid;
        f32x4 v = {0.f, 0.f, 0.f, 0.f};
        if (p < P_REAL)
            v = *reinterpret_cast<const f32x4*>(protos + (size_t)p * D_K + 4 * l);
        ushort4 w;
        w.x = f2bf(-2.f * v[0]); w.y = f2bf(-2.f * v[1]);
        w.z = f2bf(-2.f * v[2]); w.w = f2bf(-2.f * v[3]);
        *reinterpret_cast<ushort4*>(pb + (size_t)p * D_K + 4 * l) = w;
        float s = v[0]*v[0] + v[1]*v[1] + v[2]*v[2] + v[3]*v[3];
#pragma unroll
        for (int m = 32; m >= 1; m >>= 1) s += __shfl_xor(s, m, 64);
        if (l == 0) p2[p] = s;
    } else {
        int row = bid - P_PAD;
        float v[4];
        float mx = -3.4e38f;
#pragma unroll
        for (int i = 0; i < 4; ++i) {
            int c = l + 64 * i;
            v[i] = (c < C_OUT) ? lp[(size_t)row * C_OUT + c] : -3.4e38f;
            mx = fmaxf(mx, v[i]);
        }
#pragma unroll
        for (int m = 32; m >= 1; m >>= 1) mx = fmaxf(mx, __shfl_xor(mx, m, 64));
        float sum = 0.f;
#pragma unroll
        for (int i = 0; i < 4; ++i) {
            int c = l + 64 * i;
            if (c < C_OUT) { v[i] = expf(v[i] - mx); sum += v[i]; }
        }
#pragma unroll
        for (int m = 32; m >= 1; m >>= 1) sum += __shfl_xor(sum, m, 64);
        float inv = 1.f / sum;
#pragma unroll
        for (int i = 0; i < 4; ++i) {
            int c = l + 64 * i;
            if (c < C_OUT) ds[(size_t)row * C_OUT + c] = v[i] * inv;
        }
    }
}

// --- main: read-once fused distance+min --------------------------------
// grid 256 = 128 b x 2 wh-halves, 512 threads (8 waves), 1 block/CU.
// Each wave: 64 p-rows resident (af[4][8]); 8 waves = all 512 protos,
// so each block streams its xs half exactly once (103 MB total).
// Per tile: 16 fp32/thread -> bf16 swizzled LDS + x2; 64 MFMA/wave;
// double-buffered, ONE barrier per tile.
__global__ __launch_bounds__(512, 2)
void proto_min_kernel(const float* __restrict__ xs,
                      const unsigned short* __restrict__ pb,
                      float* __restrict__ pm) {
    __shared__ unsigned short Xs[2][TILE_USH];     // 32 KB
    __shared__ float x2buf[2][8*68 + 8];           // bank-padded, ~4.4 KB

    const int tid  = threadIdx.x;
    const int wv   = tid >> 6;    // 0..7
    const int lane = tid & 63;
    const int g    = lane >> 4;   // 0..3
    const int lr   = lane & 15;   // 0..15

    const int b   = blockIdx.x >> 1;
    const int whh = blockIdx.x & 1;

    const float* xb = xs + (size_t)b * (D_K * WH) + whh * WHH;

    // A fragments: -2*proto bf16, 64 rows x full K per wave
    bf16x8 af[4][8];
#pragma unroll
    for (int mf = 0; mf < 4; ++mf) {
        const unsigned short* rp = pb + (size_t)(64*wv + 16*mf + lr) * D_K + 8*g;
#pragma unroll
        for (int ks = 0; ks < 8; ++ks)
            af[mf][ks] = *reinterpret_cast<const bf16x8*>(rp + 32*ks);
    }

    const int n4 = tid & 7;    // col-quad within tile (8 quads x 4 cols)
    const int kq = tid >> 3;   // 0..63  (k-quad; 512 threads cover all 256 k)

    float rmin[4][4];
#pragma unroll
    for (int mf = 0; mf < 4; ++mf)
#pragma unroll
        for (int r = 0; r < 4; ++r) rmin[mf][r] = 3.0e38f;

    f32x4 ld[4];   // 16 floats: 4 k-rows x 4 cols

#define LOAD_TILE(T) do {                                                     \
        int colb = (T) * NT + 4 * n4;                                         \
        if (colb > WHH - 4) colb = WHH - 4;                                   \
        const float* rowp = xb + (size_t)(4*kq) * WH + colb;                  \
        _Pragma("unroll")                                                     \
        for (int r = 0; r < 4; ++r)                                           \
            ld[r] = *reinterpret_cast<const f32x4*>(rowp + r * WH);           \
    } while (0)

// element (n,k): ushort offset n*256 + ((kg ^ (n&7))<<3) + (k&7), kg=k>>3
#define STAGE_TILE(DST) do {                                                  \
        f32x4 x2a = {0.f, 0.f, 0.f, 0.f};                                     \
        _Pragma("unroll")                                                     \
        for (int r = 0; r < 4; ++r) {                                         \
            f32x4 v = ld[r];                                                  \
            x2a[0] += v[0]*v[0]; x2a[1] += v[1]*v[1];                         \
            x2a[2] += v[2]*v[2]; x2a[3] += v[3]*v[3];                         \
        }                                                                     \
        _Pragma("unroll")                                                     \
        for (int c = 0; c < 4; ++c) {                                         \
            int n = 4*n4 + c;                                                 \
            float2 f01 = make_float2(ld[0][c], ld[1][c]);                     \
            float2 f23 = make_float2(ld[2][c], ld[3][c]);                     \
            __hip_bfloat162 b01 = __float22bfloat162_rn(f01);                 \
            __hip_bfloat162 b23 = __float22bfloat162_rn(f23);                 \
            uint2 w;                                                          \
            w.x = *reinterpret_cast<unsigned int*>(&b01);                     \
            w.y = *reinterpret_cast<unsigned int*>(&b23);                     \
            int off = n*256 + (((kq >> 1) ^ (n & 7)) << 3) + ((kq & 1) << 2); \
            *reinterpret_cast<uint2*>(&Xs[DST][off]) = w;                     \
        }                                                                     \
        _Pragma("unroll")                                                     \
        for (int c = 0; c < 4; ++c) {                                         \
            x2a[c] += __shfl_xor(x2a[c], 8, 64);                              \
            x2a[c] += __shfl_xor(x2a[c], 16, 64);                             \
            x2a[c] += __shfl_xor(x2a[c], 32, 64);                             \
        }                                                                     \
        if (lane < 8) {                                                       \
            _Pragma("unroll")                                                 \
            for (int c = 0; c < 4; ++c)                                       \
                x2buf[DST][lane*68 + c*8 + wv] = x2a[c];                      \
        }                                                                     \
    } while (0)

    // prologue
    LOAD_TILE(0);
    STAGE_TILE(0);
    __syncthreads();

    int buf = 0;
    for (int t = 0; t < NTILES; ++t) {
        const bool more = (t + 1 < NTILES);

        // issue next tile's loads first; latency hides under the MFMA phase
        if (more) LOAD_TILE(t + 1);

        // x2 for this lane's 2 columns: 8 wave-partials = 2 x b128 + adds
        float x2v[2];
#pragma unroll
        for (int nf = 0; nf < 2; ++nf) {
            int n = 16*nf + lr;
            const float* xp = &x2buf[buf][(n >> 2)*68 + (n & 3)*8];
            f32x4 q0 = *reinterpret_cast<const f32x4*>(xp);
            f32x4 q1 = *reinterpret_cast<const f32x4*>(xp + 4);
            x2v[nf] = ((q0[0]+q0[1]) + (q0[2]+q0[3]))
                    + ((q1[0]+q1[1]) + (q1[2]+q1[3]));
        }

        f32x4 acc[4][2];
#pragma unroll
        for (int mf = 0; mf < 4; ++mf) {
            acc[mf][0] = (f32x4){x2v[0], x2v[0], x2v[0], x2v[0]};
            acc[mf][1] = (f32x4){x2v[1], x2v[1], x2v[1], x2v[1]};
        }

        __builtin_amdgcn_s_setprio(1);
#pragma unroll
        for (int ks = 0; ks < 8; ++ks) {
            bf16x8 bfr[2];
#pragma unroll
            for (int nf = 0; nf < 2; ++nf) {
                int n = 16*nf + lr;
                int off = n*256 + ((((ks << 2) + g) ^ (n & 7)) << 3);
                bfr[nf] = *reinterpret_cast<const bf16x8*>(&Xs[buf][off]);
            }
#pragma unroll
            for (int mf = 0; mf < 4; ++mf)
#pragma unroll
                for (int nf = 0; nf < 2; ++nf)
                    acc[mf][nf] = __builtin_amdgcn_mfma_f32_16x16x32_bf16(
                        af[mf][ks], bfr[nf], acc[mf][nf], 0, 0, 0);
        }
        __builtin_amdgcn_s_setprio(0);

        // stage next tile into the other buffer (other waves keep MFMAing)
        if (more) STAGE_TILE(buf ^ 1);

        // running min over this tile's columns
#pragma unroll
        for (int mf = 0; mf < 4; ++mf)
#pragma unroll
            for (int r = 0; r < 4; ++r)
                rmin[mf][r] = fminf(rmin[mf][r],
                                    fminf(acc[mf][0][r], acc[mf][1][r]));

        __syncthreads();
        buf ^= 1;
    }

    // min across the 16 column-lanes (flips only lr bits; g preserved)
#pragma unroll
    for (int mf = 0; mf < 4; ++mf)
#pragma unroll
        for (int r = 0; r < 4; ++r) {
            float v = rmin[mf][r];
#pragma unroll
            for (int m = 1; m <= 8; m <<= 1)
                v = fminf(v, __shfl_xor(v, m, 64));
            rmin[mf][r] = v;
        }

    if (lr == 0) {
        float* pmw = pm + ((size_t)b * 2 + whh) * P_PAD;
#pragma unroll
        for (int mf = 0; mf < 4; ++mf)
#pragma unroll
            for (int r = 0; r < 4; ++r)
                pmw[64*wv + 16*mf + 4*g + r] = rmin[mf][r];
    }
#undef LOAD_TILE
#undef STAGE_TILE
}

// --- combine halves + exp(-sqrt) + tree path products + pa @ ds -----------
__global__ __launch_bounds__(256)
void out_kernel(const float* __restrict__ pm, const float* __restrict__ p2,
                const float* __restrict__ ds, float* __restrict__ out) {
    __shared__ float sim[NLEAF];
    __shared__ float pa[NLEAF];
    int b = blockIdx.x;
    int t = threadIdx.x;
    const float* pm0 = pm + (size_t)b * 2 * P_PAD;
#pragma unroll
    for (int j = 0; j < 2; ++j) {
        int p = t + 256 * j;
        float m = fminf(pm0[p], pm0[P_PAD + p]);
        float sq = m + p2[p];
        sim[p] = expf(-sqrtf(fabsf(sq) + 1e-14f));
    }
    __syncthreads();
#pragma unroll
    for (int j = 0; j < 2; ++j) {
        int leaf = t + 256 * j;
        int node = 0;
        float prod = 1.f;
#pragma unroll
        for (int st = 0; st < TDEPTH; ++st) {
            int bit = (leaf >> (TDEPTH - 1 - st)) & 1;
            float sv = sim[node];
            prod *= bit ? sv : (1.f - sv);
            node = 2 * node + 1 + bit;
        }
        pa[leaf] = prod;
    }
    __syncthreads();
    if (t < C_OUT) {
        float a0 = 0.f, a1 = 0.f, a2 = 0.f, a3 = 0.f;
        for (int l = 0; l < NLEAF; l += 4) {
            a0 += pa[l + 0] * ds[(size_t)(l + 0) * C_OUT + t];
            a1 += pa[l + 1] * ds[(size_t)(l + 1) * C_OUT + t];
            a2 += pa[l + 2] * ds[(size_t)(l + 2) * C_OUT + t];
            a3 += pa[l + 3] * ds[(size_t)(l + 3) * C_OUT + t];
        }
        out[(size_t)b * C_OUT + t] = (a0 + a1) + (a2 + a3);
    }
}

extern "C" void kernel_launch(void* const* d_in, const int* in_sizes, int n_in,
                              void* d_out, int out_size, void* d_ws, size_t ws_size,
                              hipStream_t stream) {
    (void)in_sizes; (void)n_in; (void)out_size; (void)ws_size;
    const float* xs     = (const float*)d_in[0];
    const float* protos = (const float*)d_in[1];
    const float* lp     = (const float*)d_in[2];
    float* out = (float*)d_out;

    char* ws = (char*)d_ws;
    unsigned short* pb = (unsigned short*)(ws + WS_PB);
    float* p2   = (float*)(ws + WS_P2);
    float* dsm  = (float*)(ws + WS_DS);
    float* pm   = (float*)(ws + WS_PM);

    prep2_kernel<<<1024, 64, 0, stream>>>(protos, lp, pb, p2, dsm);
    proto_min_kernel<<<256, 512, 0, stream>>>(xs, pb, pm);
    out_kernel<<<128, 256, 0, stream>>>(pm, p2, dsm, out);
}